// Round 2
// baseline (558.380 us; speedup 1.0000x reference)
//
#include <hip/hip_runtime.h>
#include <math.h>

#define BATCH   16384
#define EMB_D   128
#define NEG_K   5
#define WAVES_PER_BLOCK 16               // 1024 threads
#define ROWS_PER_BLOCK  (WAVES_PER_BLOCK * 2)   // 2 rows per wave (half-wave each)

__device__ __forceinline__ float log_sigmoid_f(float x) {
    // stable: min(x,0) - log1p(exp(-|x|))
    return fminf(x, 0.0f) - log1pf(expf(-fabsf(x)));
}

__global__ __launch_bounds__(WAVES_PER_BLOCK * 64)
void skipgram_loss_kernel(const float* __restrict__ emb,
                          const int*   __restrict__ centers,
                          const int*   __restrict__ contexts,
                          const int*   __restrict__ negs,
                          float*       __restrict__ out) {
    const int wid  = threadIdx.x >> 6;       // wave id in block: 0..15
    const int lane = threadIdx.x & 63;       // 0..63
    const int half = lane >> 5;              // 0 or 1: which row this half-wave owns
    const int l    = lane & 31;              // lane within half-wave
    const int row  = blockIdx.x * ROWS_PER_BLOCK + wid * 2 + half;

    // row embedding = 32 float4; lane l of the half-wave takes float4 #l
    // (32 lanes x 16 B = 512 B, one full row, coalesced)
    const float4* __restrict__ embv = (const float4*)emb;
    const int RS = EMB_D / 4;                // 32 float4 per row

    // half-wave-uniform index loads (cache-broadcast)
    const int c_idx = centers[row];
    const int v_idx = contexts[row];
    int n_idx[NEG_K];
    #pragma unroll
    for (int k = 0; k < NEG_K; ++k) n_idx[k] = negs[row * NEG_K + k];

    // issue all 7 gathers before any use (7 outstanding 16B loads/lane)
    float4 u  = embv[(size_t)c_idx * RS + l];
    float4 v  = embv[(size_t)v_idx * RS + l];
    float4 nv[NEG_K];
    #pragma unroll
    for (int k = 0; k < NEG_K; ++k)
        nv[k] = embv[(size_t)n_idx[k] * RS + l];

    float pos = u.x * v.x + u.y * v.y + u.z * v.z + u.w * v.w;
    float neg = 0.0f;
    #pragma unroll
    for (int k = 0; k < NEG_K; ++k)
        neg += u.x * nv[k].x + u.y * nv[k].y + u.z * nv[k].z + u.w * nv[k].w;

    // butterfly reduction within the 32-lane half-wave (xor offsets <=16 stay in-half)
    #pragma unroll
    for (int off = 16; off > 0; off >>= 1) {
        pos += __shfl_xor(pos, off, 64);
        neg += __shfl_xor(neg, off, 64);
    }

    __shared__ float s_row[ROWS_PER_BLOCK];
    if (l == 0)
        s_row[wid * 2 + half] = log_sigmoid_f(pos) + log_sigmoid_f(-neg);
    __syncthreads();

    if (threadIdx.x == 0) {
        float t = 0.0f;
        #pragma unroll
        for (int i = 0; i < ROWS_PER_BLOCK; ++i) t += s_row[i];
        atomicAdd(out, -t);   // reference returns -sum(loss)
    }
}

extern "C" void kernel_launch(void* const* d_in, const int* in_sizes, int n_in,
                              void* d_out, int out_size, void* d_ws, size_t ws_size,
                              hipStream_t stream) {
    const float* emb      = (const float*)d_in[0];
    const int*   centers  = (const int*)d_in[1];
    const int*   contexts = (const int*)d_in[2];
    const int*   negs     = (const int*)d_in[3];
    float*       out      = (float*)d_out;

    // d_out is poisoned (0xAA) before every timed replay -> zero it (capture-safe)
    hipMemsetAsync(out, 0, sizeof(float), stream);

    const int blocks = BATCH / ROWS_PER_BLOCK;   // 512
    skipgram_loss_kernel<<<blocks, WAVES_PER_BLOCK * 64, 0, stream>>>(
        emb, centers, contexts, negs, out);
}